// Round 18
// baseline (67.247 us; speedup 1.0000x reference)
//
#include <hip/hip_runtime.h>

typedef __attribute__((ext_vector_type(4))) float f32x4;
typedef __attribute__((ext_vector_type(8))) short short8;
typedef unsigned short ushort_t;

constexpr int DM = 1024, DH = 64, S = 4096, B = 4;
// fold softmax scale 1/sqrt(64) AND log2(e) into Q so scores are in exp2 units
constexpr float QSCALE = 0.125f * 1.44269504088896340736f;
constexpr int SPLIT = 4;

// ws layout (bytes)
constexpr size_t WBT_OFF = 0;                    // Wbt: [192][1024] bf16 (W transposed)
constexpr size_t QB_OFF  = 393216;               // Qb:  [B*S][64] bf16, pre-scaled
constexpr size_t KB_OFF  = QB_OFF + 2097152;     // Kb:  [B*S][64] bf16, LINEAR
constexpr size_t VT_OFF  = KB_OFF + 2097152;     // Vtb: [B][64][S] bf16, LINEAR
constexpr size_t ML_OFF  = VT_OFF + 2097152;     // ml:  f32 [4][B*S][2]  = 512KB
constexpr size_t PO_OFF  = ML_OFF + 524288;      // po:  bf16 [4][B*S][64] = 8MB

__device__ __forceinline__ ushort_t f2bf(float f) {  // RNE f32->bf16
    unsigned u = __float_as_uint(f);
    u += 0x7FFFu + ((u >> 16) & 1u);
    return (ushort_t)(u >> 16);
}

__device__ __forceinline__ unsigned cvt_pk_bf16(float lo, float hi) {
    unsigned r;
    asm volatile("v_cvt_pk_bf16_f32 %0, %1, %2" : "=v"(r) : "v"(lo), "v"(hi));
    return r;
}

__device__ __forceinline__ void gl_lds16(const void* g, void* l) {
    __builtin_amdgcn_global_load_lds(
        (const __attribute__((address_space(1))) unsigned int*)g,
        (__attribute__((address_space(3))) unsigned int*)l, 16, 0, 0);
}

// ---------------- prep: W fp32 [1024][64] -> Wbt bf16 [192][1024] (transposed) ----
__global__ __launch_bounds__(256) void prep_w_kernel(
    const float* __restrict__ Wq, const float* __restrict__ Wk,
    const float* __restrict__ Wv, ushort_t* __restrict__ wbt)
{
    const int n = blockIdx.x;            // 0..191 : [Q(0-63)|K(64-127)|V(128-191)]
    const int p = n >> 6, d = n & 63;
    const float* W = (p == 0) ? Wq : (p == 1) ? Wk : Wv;
    const int k0 = threadIdx.x * 4;
    ushort4 pack;
    pack.x = f2bf(W[(k0 + 0) * DH + d]);
    pack.y = f2bf(W[(k0 + 1) * DH + d]);
    pack.z = f2bf(W[(k0 + 2) * DH + d]);
    pack.w = f2bf(W[(k0 + 3) * DH + d]);
    *reinterpret_cast<ushort4*>(wbt + (size_t)n * DM + k0) = pack;
}

// ---------------- QKV projection: cooperative staged GEMM, 4-wave blocks ----------
// R10 structure reshaped: block = 256 thr (4 waves) on the SAME 32 rows, SAME
// 16KB/step staging and swizzles. Wave = (sub = m-half of 16 rows, np = n-half
// of 6 nt) -> 6 MFMA/step/wave. Staging: 16 tasks over 4 waves = 4 gl_lds/thread
// (queue depth 2->4) and 4 blocks/CU instead of 2 (LDS 32KB, 16 waves/CU same)
// -> 4 independent barrier groups overlap each other's staging drains (m114).
__global__ __launch_bounds__(256, 4) void qkv_mfma_kernel(
    const float* __restrict__ x, const ushort_t* __restrict__ wbt,
    const float* __restrict__ bq, const float* __restrict__ bk,
    const float* __restrict__ bv,
    ushort_t* __restrict__ qb, ushort_t* __restrict__ kb, ushort_t* __restrict__ vt)
{
    __shared__ uint4 AsU[2][256];   // 2 x 4KB : [32 r][128B], 16B-chunk swz ch^(row&7)
    __shared__ uint4 BsU[2][768];   // 2 x 12KB: [192 n][64B], 16B-chunk swz ch^(row&3)

    const int tid = threadIdx.x;
    const int wid = tid >> 6, lane = tid & 63;
    const int q16 = lane & 15, lg = lane >> 4;
    const int sub = wid & 1, np = wid >> 1;   // np in {0,1}: 6 nt each
    const int r0 = blockIdx.x * 32;
    const char* xB = (const char*)x;
    const char* wB = (const char*)wbt;

    auto task = [&](int tk, int buf, int kk) {
        if (tk < 4) {
            gl_lds16(xB + (size_t)(r0 + tk * 8 + (lane >> 3)) * 4096 + kk * 4
                        + (((lane & 7) ^ (lane >> 3)) << 4),
                     (char*)&AsU[buf][0] + tk * 1024 + lane * 16);
        } else {
            const int sg = tk - 4;   // B seg 0..11 (1KB = 16 n-rows x 64B)
            gl_lds16(wB + (size_t)(sg * 16 + (lane >> 2)) * 2048 + kk * 2
                        + ((((lane & 3) ^ ((lane >> 2) & 3))) << 4),
                     (char*)&BsU[buf][0] + sg * 1024 + lane * 16);
        }
    };

    f32x4 acc[6];
#pragma unroll
    for (int j = 0; j < 6; ++j) acc[j] = {0.f, 0.f, 0.f, 0.f};

    // prologue: 16 tasks over 4 waves, 4 each (back-to-back = deep queue)
    task(4 * wid + 0, 0, 0);
    task(4 * wid + 1, 0, 0);
    task(4 * wid + 2, 0, 0);
    task(4 * wid + 3, 0, 0);
    __syncthreads();

    const int row = sub * 16 + q16;
    for (int s = 0; s < 32; ++s) {
        const int buf = s & 1;
        if (s + 1 < 32) {
            task(4 * wid + 0, buf ^ 1, (s + 1) * 32);
            task(4 * wid + 1, buf ^ 1, (s + 1) * 32);
            task(4 * wid + 2, buf ^ 1, (s + 1) * 32);
            task(4 * wid + 3, buf ^ 1, (s + 1) * 32);
        }
        const char* AsC = (const char*)&AsU[buf][0];
        const char* BsC = (const char*)&BsU[buf][0];
        const f32x4 a0 = *(const f32x4*)(AsC + row * 128 + (((2 * lg) ^ (row & 7)) << 4));
        const f32x4 a1 = *(const f32x4*)(AsC + row * 128 + (((2 * lg + 1) ^ (row & 7)) << 4));
        short8 Af;
        Af[0] = (short)f2bf(a0[0]); Af[1] = (short)f2bf(a0[1]);
        Af[2] = (short)f2bf(a0[2]); Af[3] = (short)f2bf(a0[3]);
        Af[4] = (short)f2bf(a1[0]); Af[5] = (short)f2bf(a1[1]);
        Af[6] = (short)f2bf(a1[2]); Af[7] = (short)f2bf(a1[3]);
        __builtin_amdgcn_s_setprio(1);
#pragma unroll
        for (int j = 0; j < 6; ++j) {
            const int nt = np * 6 + j;
            const short8 Bf = *(const short8*)(
                BsC + (nt * 16 + q16) * 64 + ((lg ^ (q16 & 3)) << 4));
            acc[j] = __builtin_amdgcn_mfma_f32_16x16x32_bf16(Af, Bf, acc[j], 0, 0, 0);
        }
        __builtin_amdgcn_s_setprio(0);
        __syncthreads();
    }

    // Epilogue: C/D layout row=(lane>>4)*4+reg, col=lane&15. Kb/Vt LINEAR.
#pragma unroll
    for (int j = 0; j < 6; ++j) {
        const int nt = np * 6 + j;
        const int p = nt >> 2, d = ((nt & 3) << 4) + q16;
        const float* bp = (p == 0) ? bq : (p == 1) ? bk : bv;
        const float bb = bp[d];
#pragma unroll
        for (int r = 0; r < 4; ++r) {
            const int m = r0 + sub * 16 + (lg << 2) + r;
            const float v = acc[j][r] + bb;
            if (p == 0) {
                qb[(size_t)m * 64 + d] = f2bf(v * QSCALE);
            } else if (p == 1) {
                kb[(size_t)m * 64 + d] = f2bf(v);
            } else {
                const int bb_ = m >> 12, sx = m & 4095;
                vt[(size_t)bb_ * 262144 + (size_t)d * 4096 + sx] = f2bf(v);
            }
        }
    }
}

// ---------------- causal flash attention: QBLK=64, KVBLK=128, split-KV x4 ----------
// R17 body (XCD z-parity KV partition: each L2 serves a 2MB half of the batch KV).
__global__ __launch_bounds__(256, 4) void attn_mfma_kernel(
    const ushort_t* __restrict__ qb, const ushort_t* __restrict__ kb,
    const ushort_t* __restrict__ vt, ushort_t* __restrict__ po,
    float* __restrict__ ml)
{
    __shared__ uint4 LsU[2][2048];     // 64KB: [buf][K 16KB | Vt 16KB], 16B slots
    __shared__ uint4 PsU[4][256];      // 16KB: per-wave P [16 q][128 kv] bf16

    const int tid = threadIdx.x;
    const int wid = tid >> 6, lane = tid & 63;
    const int q16 = lane & 15, lg = lane >> 4;

    // XCD-parity decode: xcd = linear&7; b = xcd>>1; z parity tied to xcd parity.
    const int linear = blockIdx.x;            // 0..1023
    const int xcd  = linear & 7;
    const int rest = linear >> 3;             // 0..127
    const int b    = xcd >> 1;
    const int z    = ((rest & 1) << 1) | (xcd & 1);   // 0..3
    const int qt   = 63 - (rest >> 1);        // heavy q-blocks first

    const int qrow = qt * 64 + wid * 16 + q16;   // this lane's q (C/D column)
    const ushort_t* Qb = qb + (size_t)b * S * 64;
    const char* KbB = (const char*)(kb + (size_t)b * S * 64);
    const char* VtB = (const char*)(vt + (size_t)b * 64 * S);

    const short8 qf0 = *(const short8*)(Qb + (size_t)qrow * 64 + lg * 8);
    const short8 qf1 = *(const short8*)(Qb + (size_t)qrow * 64 + 32 + lg * 8);

    f32x4 o[4];
#pragma unroll
    for (int nt = 0; nt < 4; ++nt) o[nt] = {0.f, 0.f, 0.f, 0.f};
    float m = -1e30f, l = 0.f;

    char* PsC = (char*)&PsU[wid][0];
    const int ntiles = (qt >> 1) + 1;            // 128-wide kv tiles

    // Stage tile t (128 kv) into buf: K [128 rows][128B] + Vt [64 d][256B].
    auto stage = [&](int t, int buf) {
        const int kv0 = t * 128;
#pragma unroll
        for (int i = 0; i < 8; ++i) {
            const int slot = i * 256 + tid;
            char* dst = (char*)&LsU[buf][0] + slot * 16;
            if (slot < 1024) {
                const int row = slot >> 3, ch = slot & 7;
                gl_lds16(KbB + (size_t)(kv0 + row) * 128 + ((ch ^ (row & 7)) << 4), dst);
            } else {
                const int s2 = slot - 1024;
                const int d = s2 >> 4, ch = s2 & 15;
                gl_lds16(VtB + (size_t)d * (S * 2) + kv0 * 2 + ((ch ^ (d & 15)) << 4), dst);
            }
        }
    };

    int buf = 0;
    if (z < ntiles) stage(z, 0);
    __syncthreads();

    for (int t = z; t < ntiles; t += SPLIT) {
        if (t + SPLIT < ntiles) stage(t + SPLIT, buf ^ 1);  // overlaps compute below
        const char* KsC = (const char*)&LsU[buf][0];
        const char* VsC = KsC + 16384;
        const int kv0 = t * 128;

        // ---- S^T = K . Q^T : D[kv 128][q 16], lane q=q16, kv = kv0+16mt+4lg+r ----
        f32x4 st[8];
#pragma unroll
        for (int mt = 0; mt < 8; ++mt) st[mt] = {0.f, 0.f, 0.f, 0.f};
#pragma unroll
        for (int ks = 0; ks < 2; ++ks) {
#pragma unroll
            for (int mg = 0; mg < 2; ++mg) {
                short8 kf[4];
#pragma unroll
                for (int j = 0; j < 4; ++j) {
                    const int mt = mg * 4 + j;
                    kf[j] = *(const short8*)(
                        KsC + (mt * 16 + q16) * 128 + (((lg + 4 * ks) ^ (q16 & 7)) << 4));
                }
                __builtin_amdgcn_s_setprio(1);
#pragma unroll
                for (int j = 0; j < 4; ++j)
                    st[mg * 4 + j] = __builtin_amdgcn_mfma_f32_16x16x32_bf16(
                        kf[j], (ks ? qf1 : qf0), st[mg * 4 + j], 0, 0, 0);
                __builtin_amdgcn_s_setprio(0);
            }
        }

        // ---- causal mask: only the diagonal tile (t == ntiles-1) ----
        if (t == ntiles - 1) {
#pragma unroll
            for (int mt = 0; mt < 8; ++mt)
#pragma unroll
                for (int r = 0; r < 4; ++r)
                    if (kv0 + mt * 16 + (lg << 2) + r > qrow) st[mt][r] = -1e30f;
        }

        // ---- online softmax (log2 units), per q-column q16 ----
        float tm = -1e30f;
#pragma unroll
        for (int mt = 0; mt < 8; ++mt)
#pragma unroll
            for (int r = 0; r < 4; ++r) tm = fmaxf(tm, st[mt][r]);
        tm = fmaxf(tm, __shfl_xor(tm, 16));
        tm = fmaxf(tm, __shfl_xor(tm, 32));

        if (__all(tm <= m)) {
            // fast path: running max unchanged -> no rescale, no corr shuffles
            float ps = 0.f;
#pragma unroll
            for (int mt = 0; mt < 8; ++mt)
#pragma unroll
                for (int r = 0; r < 4; ++r) {
                    const float pv = exp2f(st[mt][r] - m);
                    st[mt][r] = pv;
                    ps += pv;
                }
            ps += __shfl_xor(ps, 16);
            ps += __shfl_xor(ps, 32);
            l += ps;
        } else {
            const float mn = fmaxf(m, tm);
            const float corr = exp2f(m - mn);
            float ps = 0.f;
#pragma unroll
            for (int mt = 0; mt < 8; ++mt)
#pragma unroll
                for (int r = 0; r < 4; ++r) {
                    const float pv = exp2f(st[mt][r] - mn);
                    st[mt][r] = pv;
                    ps += pv;
                }
            ps += __shfl_xor(ps, 16);
            ps += __shfl_xor(ps, 32);
            l = l * corr + ps;
            m = mn;
            // o rows are q = 4lg+r but corr is per q-col q16 -> redistribute.
            float corr_row[4];
#pragma unroll
            for (int r = 0; r < 4; ++r) corr_row[r] = __shfl(corr, (lg << 2) | r);
#pragma unroll
            for (int nt = 0; nt < 4; ++nt)
#pragma unroll
                for (int r = 0; r < 4; ++r) o[nt][r] *= corr_row[r];
        }

        // ---- P (bf16 via cvt_pk) -> per-wave LDS [16q][256B], swizzled chunks ----
#pragma unroll
        for (int mt = 0; mt < 8; ++mt) {
            uint2 w;
            w.x = cvt_pk_bf16(st[mt][0], st[mt][1]);
            w.y = cvt_pk_bf16(st[mt][2], st[mt][3]);
            const int ch = (2 * mt + (lg >> 1)) ^ q16;
            *reinterpret_cast<uint2*>(PsC + q16 * 256 + ch * 16 + (lg & 1) * 8) = w;
        }

        // ---- O += P . V : D[q][d], 4 ks-slices of 32 kv ----
        __builtin_amdgcn_s_setprio(1);
#pragma unroll
        for (int ks = 0; ks < 4; ++ks) {
            const short8 pa = *reinterpret_cast<const short8*>(
                PsC + q16 * 256 + (((4 * ks + lg) ^ q16) << 4));
#pragma unroll
            for (int nt = 0; nt < 4; ++nt) {
                const short8 vf = *(const short8*)(
                    VsC + (nt * 16 + q16) * 256 + (((ks * 4 + lg) ^ q16) << 4));
                o[nt] = __builtin_amdgcn_mfma_f32_16x16x32_bf16(pa, vf, o[nt], 0, 0, 0);
            }
        }
        __builtin_amdgcn_s_setprio(0);

        __syncthreads();   // drains stage vmcnt; guards buf reuse
        buf ^= 1;
    }

    // ---- partial write: o unnormalized (bf16), (m,l) f32; each wave owns rows ----
    const int rowbase = qt * 64 + wid * 16;
    const size_t zb = (size_t)z * B * S + (size_t)b * S;
#pragma unroll
    for (int nt = 0; nt < 4; ++nt)
#pragma unroll
        for (int r = 0; r < 4; ++r)
            po[(zb + rowbase + (lg << 2) + r) * 64 + nt * 16 + q16] = f2bf(o[nt][r]);
    if (lg == 0) {
        ml[(zb + rowbase + q16) * 2 + 0] = m;
        ml[(zb + rowbase + q16) * 2 + 1] = l;
    }
}

// ---------------- merge: out = sum_z c_z * o_z / sum_z c_z * l_z ----------------
__global__ __launch_bounds__(256) void merge_kernel(
    const ushort_t* __restrict__ po, const float* __restrict__ ml,
    float* __restrict__ out)
{
    const int idx = blockIdx.x * 256 + threadIdx.x;   // 0 .. B*S*8-1
    const int row = idx >> 3, c8 = idx & 7;

    float mv[SPLIT], lv[SPLIT];
#pragma unroll
    for (int zz = 0; zz < SPLIT; ++zz) {
        const float2 t = *(const float2*)(ml + ((size_t)zz * B * S + row) * 2);
        mv[zz] = t.x; lv[zz] = t.y;
    }
    const float mm = fmaxf(fmaxf(mv[0], mv[1]), fmaxf(mv[2], mv[3]));
    float L = 0.f, cz[SPLIT];
#pragma unroll
    for (int zz = 0; zz < SPLIT; ++zz) { cz[zz] = exp2f(mv[zz] - mm); L += lv[zz] * cz[zz]; }
    const float inv = 1.0f / L;

    float acc[8];
#pragma unroll
    for (int e = 0; e < 8; ++e) acc[e] = 0.f;
#pragma unroll
    for (int zz = 0; zz < SPLIT; ++zz) {
        const uint4 pk = *(const uint4*)(po + ((size_t)zz * B * S + row) * 64 + c8 * 8);
        const unsigned w[4] = {pk.x, pk.y, pk.z, pk.w};
#pragma unroll
        for (int i = 0; i < 4; ++i) {
            acc[2 * i + 0] += cz[zz] * __uint_as_float((w[i] & 0xFFFFu) << 16);
            acc[2 * i + 1] += cz[zz] * __uint_as_float((w[i] >> 16) << 16);
        }
    }
    float4 o0 = make_float4(acc[0] * inv, acc[1] * inv, acc[2] * inv, acc[3] * inv);
    float4 o1 = make_float4(acc[4] * inv, acc[5] * inv, acc[6] * inv, acc[7] * inv);
    *(float4*)(out + (size_t)row * 64 + c8 * 8 + 0) = o0;
    *(float4*)(out + (size_t)row * 64 + c8 * 8 + 4) = o1;
}

extern "C" void kernel_launch(void* const* d_in, const int* in_sizes, int n_in,
                              void* d_out, int out_size, void* d_ws, size_t ws_size,
                              hipStream_t stream) {
    const float* x  = (const float*)d_in[0];
    const float* Wq = (const float*)d_in[1];
    const float* bq = (const float*)d_in[2];
    const float* Wk = (const float*)d_in[3];
    const float* bk = (const float*)d_in[4];
    const float* Wv = (const float*)d_in[5];
    const float* bv = (const float*)d_in[6];
    float* out = (float*)d_out;

    char* ws = (char*)d_ws;
    ushort_t* wbt = (ushort_t*)(ws + WBT_OFF);
    ushort_t* qbp = (ushort_t*)(ws + QB_OFF);
    ushort_t* kbp = (ushort_t*)(ws + KB_OFF);
    ushort_t* vtp = (ushort_t*)(ws + VT_OFF);
    float*    mlp = (float*)(ws + ML_OFF);
    ushort_t* pop = (ushort_t*)(ws + PO_OFF);

    hipLaunchKernelGGL(prep_w_kernel, dim3(192), dim3(256), 0, stream, Wq, Wk, Wv, wbt);
    hipLaunchKernelGGL(qkv_mfma_kernel, dim3(512), dim3(256), 0, stream,
                       x, wbt, bq, bk, bv, qbp, kbp, vtp);
    hipLaunchKernelGGL(attn_mfma_kernel, dim3(1024), dim3(256), 0, stream,
                       qbp, kbp, vtp, pop, mlp);
    hipLaunchKernelGGL(merge_kernel, dim3(512), dim3(256), 0, stream, pop, mlp, out);
}

// Round 19
// 64.582 us; speedup vs baseline: 1.0413x; 1.0413x over previous
//
#include <hip/hip_runtime.h>

typedef __attribute__((ext_vector_type(4))) float f32x4;
typedef __attribute__((ext_vector_type(8))) short short8;
typedef unsigned short ushort_t;

constexpr int DM = 1024, DH = 64, S = 4096, B = 4;
// fold softmax scale 1/sqrt(64) AND log2(e) into Q so scores are in exp2 units
constexpr float QSCALE = 0.125f * 1.44269504088896340736f;
constexpr int SPLIT = 4;

// ws layout (bytes)
constexpr size_t WBT_OFF = 0;                    // Wbt: [192][1024] bf16 (W transposed)
constexpr size_t QB_OFF  = 393216;               // Qb:  [B*S][64] bf16, pre-scaled
constexpr size_t KB_OFF  = QB_OFF + 2097152;     // Kb:  [B*S][64] bf16, LINEAR
constexpr size_t VT_OFF  = KB_OFF + 2097152;     // Vtb: [B][64][S] bf16, LINEAR
constexpr size_t ML_OFF  = VT_OFF + 2097152;     // ml:  f32 [4][B*S][2]  = 512KB
constexpr size_t PO_OFF  = ML_OFF + 524288;      // po:  bf16 [4][B*S][64] = 8MB

__device__ __forceinline__ ushort_t f2bf(float f) {  // RNE f32->bf16
    unsigned u = __float_as_uint(f);
    u += 0x7FFFu + ((u >> 16) & 1u);
    return (ushort_t)(u >> 16);
}

__device__ __forceinline__ unsigned cvt_pk_bf16(float lo, float hi) {
    unsigned r;
    asm volatile("v_cvt_pk_bf16_f32 %0, %1, %2" : "=v"(r) : "v"(lo), "v"(hi));
    return r;
}

__device__ __forceinline__ void gl_lds16(const void* g, void* l) {
    __builtin_amdgcn_global_load_lds(
        (const __attribute__((address_space(1))) unsigned int*)g,
        (__attribute__((address_space(3))) unsigned int*)l, 16, 0, 0);
}

// ---------------- prep: W fp32 [1024][64] -> Wbt bf16 [192][1024] (transposed) ----
__global__ __launch_bounds__(256) void prep_w_kernel(
    const float* __restrict__ Wq, const float* __restrict__ Wk,
    const float* __restrict__ Wv, ushort_t* __restrict__ wbt)
{
    const int n = blockIdx.x;            // 0..191 : [Q(0-63)|K(64-127)|V(128-191)]
    const int p = n >> 6, d = n & 63;
    const float* W = (p == 0) ? Wq : (p == 1) ? Wk : Wv;
    const int k0 = threadIdx.x * 4;
    ushort4 pack;
    pack.x = f2bf(W[(k0 + 0) * DH + d]);
    pack.y = f2bf(W[(k0 + 1) * DH + d]);
    pack.z = f2bf(W[(k0 + 2) * DH + d]);
    pack.w = f2bf(W[(k0 + 3) * DH + d]);
    *reinterpret_cast<ushort4*>(wbt + (size_t)n * DM + k0) = pack;
}

// ---------------- QKV projection: cooperative staged GEMM (R10 best, 8-wave) ------
__global__ __launch_bounds__(512, 4) void qkv_mfma_kernel(
    const float* __restrict__ x, const ushort_t* __restrict__ wbt,
    const float* __restrict__ bq, const float* __restrict__ bk,
    const float* __restrict__ bv,
    ushort_t* __restrict__ qb, ushort_t* __restrict__ kb, ushort_t* __restrict__ vt)
{
    __shared__ uint4 AsU[2][256];   // 2 x 4KB : [32 r][128B], 16B-chunk swz ch^(row&7)
    __shared__ uint4 BsU[2][768];   // 2 x 12KB: [192 n][64B], 16B-chunk swz ch^(row&3)

    const int tid = threadIdx.x;
    const int wid = tid >> 6, lane = tid & 63;
    const int q16 = lane & 15, lg = lane >> 4;
    const int sub = wid & 1, np = wid >> 1;
    const int r0 = blockIdx.x * 32;
    const char* xB = (const char*)x;
    const char* wB = (const char*)wbt;

    auto task = [&](int tk, int buf, int kk) {
        if (tk < 4) {
            gl_lds16(xB + (size_t)(r0 + tk * 8 + (lane >> 3)) * 4096 + kk * 4
                        + (((lane & 7) ^ (lane >> 3)) << 4),
                     (char*)&AsU[buf][0] + tk * 1024 + lane * 16);
        } else {
            const int sg = tk - 4;   // B seg 0..11 (1KB = 16 n-rows x 64B)
            gl_lds16(wB + (size_t)(sg * 16 + (lane >> 2)) * 2048 + kk * 2
                        + ((((lane & 3) ^ ((lane >> 2) & 3))) << 4),
                     (char*)&BsU[buf][0] + sg * 1024 + lane * 16);
        }
    };

    f32x4 acc[3];
#pragma unroll
    for (int j = 0; j < 3; ++j) acc[j] = {0.f, 0.f, 0.f, 0.f};

    task(2 * wid, 0, 0);
    task(2 * wid + 1, 0, 0);
    __syncthreads();

    const int row = sub * 16 + q16;
    for (int s = 0; s < 32; ++s) {
        const int buf = s & 1;
        if (s + 1 < 32) {
            task(2 * wid, buf ^ 1, (s + 1) * 32);
            task(2 * wid + 1, buf ^ 1, (s + 1) * 32);
        }
        const char* AsC = (const char*)&AsU[buf][0];
        const char* BsC = (const char*)&BsU[buf][0];
        const f32x4 a0 = *(const f32x4*)(AsC + row * 128 + (((2 * lg) ^ (row & 7)) << 4));
        const f32x4 a1 = *(const f32x4*)(AsC + row * 128 + (((2 * lg + 1) ^ (row & 7)) << 4));
        short8 Af;
        Af[0] = (short)f2bf(a0[0]); Af[1] = (short)f2bf(a0[1]);
        Af[2] = (short)f2bf(a0[2]); Af[3] = (short)f2bf(a0[3]);
        Af[4] = (short)f2bf(a1[0]); Af[5] = (short)f2bf(a1[1]);
        Af[6] = (short)f2bf(a1[2]); Af[7] = (short)f2bf(a1[3]);
        __builtin_amdgcn_s_setprio(1);
#pragma unroll
        for (int j = 0; j < 3; ++j) {
            const int nt = np * 3 + j;
            const short8 Bf = *(const short8*)(
                BsC + (nt * 16 + q16) * 64 + ((lg ^ (q16 & 3)) << 4));
            acc[j] = __builtin_amdgcn_mfma_f32_16x16x32_bf16(Af, Bf, acc[j], 0, 0, 0);
        }
        __builtin_amdgcn_s_setprio(0);
        __syncthreads();
    }

    // Epilogue: C/D layout row=(lane>>4)*4+reg, col=lane&15. Kb/Vt LINEAR.
#pragma unroll
    for (int j = 0; j < 3; ++j) {
        const int nt = np * 3 + j;
        const int p = nt >> 2, d = ((nt & 3) << 4) + q16;
        const float* bp = (p == 0) ? bq : (p == 1) ? bk : bv;
        const float bb = bp[d];
#pragma unroll
        for (int r = 0; r < 4; ++r) {
            const int m = r0 + sub * 16 + (lg << 2) + r;
            const float v = acc[j][r] + bb;
            if (p == 0) {
                qb[(size_t)m * 64 + d] = f2bf(v * QSCALE);
            } else if (p == 1) {
                kb[(size_t)m * 64 + d] = f2bf(v);
            } else {
                const int bb_ = m >> 12, sx = m & 4095;
                vt[(size_t)bb_ * 262144 + (size_t)d * 4096 + sx] = f2bf(v);
            }
        }
    }
}

// ---------------- causal flash attention: QBLK=64, KVBLK=128, split-KV x4 ----------
// R17 body: XCD z-parity KV partition (xcd = 2b + (z&1)) so each XCD's L2 serves
// a 2MB half of the batch's 4MB K/V instead of thrashing at exactly L2 capacity.
__global__ __launch_bounds__(256, 4) void attn_mfma_kernel(
    const ushort_t* __restrict__ qb, const ushort_t* __restrict__ kb,
    const ushort_t* __restrict__ vt, ushort_t* __restrict__ po,
    float* __restrict__ ml)
{
    __shared__ uint4 LsU[2][2048];     // 64KB: [buf][K 16KB | Vt 16KB], 16B slots
    __shared__ uint4 PsU[4][256];      // 16KB: per-wave P [16 q][128 kv] bf16

    const int tid = threadIdx.x;
    const int wid = tid >> 6, lane = tid & 63;
    const int q16 = lane & 15, lg = lane >> 4;

    // XCD-parity decode: xcd = linear&7; b = xcd>>1; z parity tied to xcd parity.
    const int linear = blockIdx.x;            // 0..1023
    const int xcd  = linear & 7;
    const int rest = linear >> 3;             // 0..127
    const int b    = xcd >> 1;
    const int z    = ((rest & 1) << 1) | (xcd & 1);   // 0..3
    const int qt   = 63 - (rest >> 1);        // heavy q-blocks first

    const int qrow = qt * 64 + wid * 16 + q16;   // this lane's q (C/D column)
    const ushort_t* Qb = qb + (size_t)b * S * 64;
    const char* KbB = (const char*)(kb + (size_t)b * S * 64);
    const char* VtB = (const char*)(vt + (size_t)b * 64 * S);

    const short8 qf0 = *(const short8*)(Qb + (size_t)qrow * 64 + lg * 8);
    const short8 qf1 = *(const short8*)(Qb + (size_t)qrow * 64 + 32 + lg * 8);

    f32x4 o[4];
#pragma unroll
    for (int nt = 0; nt < 4; ++nt) o[nt] = {0.f, 0.f, 0.f, 0.f};
    float m = -1e30f, l = 0.f;

    char* PsC = (char*)&PsU[wid][0];
    const int ntiles = (qt >> 1) + 1;            // 128-wide kv tiles

    // Stage tile t (128 kv) into buf: K [128 rows][128B] + Vt [64 d][256B].
    auto stage = [&](int t, int buf) {
        const int kv0 = t * 128;
#pragma unroll
        for (int i = 0; i < 8; ++i) {
            const int slot = i * 256 + tid;
            char* dst = (char*)&LsU[buf][0] + slot * 16;
            if (slot < 1024) {
                const int row = slot >> 3, ch = slot & 7;
                gl_lds16(KbB + (size_t)(kv0 + row) * 128 + ((ch ^ (row & 7)) << 4), dst);
            } else {
                const int s2 = slot - 1024;
                const int d = s2 >> 4, ch = s2 & 15;
                gl_lds16(VtB + (size_t)d * (S * 2) + kv0 * 2 + ((ch ^ (d & 15)) << 4), dst);
            }
        }
    };

    int buf = 0;
    if (z < ntiles) stage(z, 0);
    __syncthreads();

    for (int t = z; t < ntiles; t += SPLIT) {
        if (t + SPLIT < ntiles) stage(t + SPLIT, buf ^ 1);  // overlaps compute below
        const char* KsC = (const char*)&LsU[buf][0];
        const char* VsC = KsC + 16384;
        const int kv0 = t * 128;

        // ---- S^T = K . Q^T : D[kv 128][q 16], lane q=q16, kv = kv0+16mt+4lg+r ----
        f32x4 st[8];
#pragma unroll
        for (int mt = 0; mt < 8; ++mt) st[mt] = {0.f, 0.f, 0.f, 0.f};
#pragma unroll
        for (int ks = 0; ks < 2; ++ks) {
#pragma unroll
            for (int mg = 0; mg < 2; ++mg) {
                short8 kf[4];
#pragma unroll
                for (int j = 0; j < 4; ++j) {
                    const int mt = mg * 4 + j;
                    kf[j] = *(const short8*)(
                        KsC + (mt * 16 + q16) * 128 + (((lg + 4 * ks) ^ (q16 & 7)) << 4));
                }
                __builtin_amdgcn_s_setprio(1);
#pragma unroll
                for (int j = 0; j < 4; ++j)
                    st[mg * 4 + j] = __builtin_amdgcn_mfma_f32_16x16x32_bf16(
                        kf[j], (ks ? qf1 : qf0), st[mg * 4 + j], 0, 0, 0);
                __builtin_amdgcn_s_setprio(0);
            }
        }

        // ---- causal mask: only the diagonal tile (t == ntiles-1) ----
        if (t == ntiles - 1) {
#pragma unroll
            for (int mt = 0; mt < 8; ++mt)
#pragma unroll
                for (int r = 0; r < 4; ++r)
                    if (kv0 + mt * 16 + (lg << 2) + r > qrow) st[mt][r] = -1e30f;
        }

        // ---- online softmax (log2 units), per q-column q16 ----
        float tm = -1e30f;
#pragma unroll
        for (int mt = 0; mt < 8; ++mt)
#pragma unroll
            for (int r = 0; r < 4; ++r) tm = fmaxf(tm, st[mt][r]);
        tm = fmaxf(tm, __shfl_xor(tm, 16));
        tm = fmaxf(tm, __shfl_xor(tm, 32));

        if (__all(tm <= m)) {
            // fast path: running max unchanged -> no rescale, no corr shuffles
            float ps = 0.f;
#pragma unroll
            for (int mt = 0; mt < 8; ++mt)
#pragma unroll
                for (int r = 0; r < 4; ++r) {
                    const float pv = exp2f(st[mt][r] - m);
                    st[mt][r] = pv;
                    ps += pv;
                }
            ps += __shfl_xor(ps, 16);
            ps += __shfl_xor(ps, 32);
            l += ps;
        } else {
            const float mn = fmaxf(m, tm);
            const float corr = exp2f(m - mn);
            float ps = 0.f;
#pragma unroll
            for (int mt = 0; mt < 8; ++mt)
#pragma unroll
                for (int r = 0; r < 4; ++r) {
                    const float pv = exp2f(st[mt][r] - mn);
                    st[mt][r] = pv;
                    ps += pv;
                }
            ps += __shfl_xor(ps, 16);
            ps += __shfl_xor(ps, 32);
            l = l * corr + ps;
            m = mn;
            // o rows are q = 4lg+r but corr is per q-col q16 -> redistribute.
            float corr_row[4];
#pragma unroll
            for (int r = 0; r < 4; ++r) corr_row[r] = __shfl(corr, (lg << 2) | r);
#pragma unroll
            for (int nt = 0; nt < 4; ++nt)
#pragma unroll
                for (int r = 0; r < 4; ++r) o[nt][r] *= corr_row[r];
        }

        // ---- P (bf16 via cvt_pk) -> per-wave LDS [16q][256B], swizzled chunks ----
#pragma unroll
        for (int mt = 0; mt < 8; ++mt) {
            uint2 w;
            w.x = cvt_pk_bf16(st[mt][0], st[mt][1]);
            w.y = cvt_pk_bf16(st[mt][2], st[mt][3]);
            const int ch = (2 * mt + (lg >> 1)) ^ q16;
            *reinterpret_cast<uint2*>(PsC + q16 * 256 + ch * 16 + (lg & 1) * 8) = w;
        }

        // ---- O += P . V : D[q][d], 4 ks-slices of 32 kv ----
        __builtin_amdgcn_s_setprio(1);
#pragma unroll
        for (int ks = 0; ks < 4; ++ks) {
            const short8 pa = *reinterpret_cast<const short8*>(
                PsC + q16 * 256 + (((4 * ks + lg) ^ q16) << 4));
#pragma unroll
            for (int nt = 0; nt < 4; ++nt) {
                const short8 vf = *(const short8*)(
                    VsC + (nt * 16 + q16) * 256 + (((ks * 4 + lg) ^ q16) << 4));
                o[nt] = __builtin_amdgcn_mfma_f32_16x16x32_bf16(pa, vf, o[nt], 0, 0, 0);
            }
        }
        __builtin_amdgcn_s_setprio(0);

        __syncthreads();   // drains stage vmcnt; guards buf reuse
        buf ^= 1;
    }

    // ---- partial write: o unnormalized (bf16), (m,l) f32; each wave owns rows ----
    const int rowbase = qt * 64 + wid * 16;
    const size_t zb = (size_t)z * B * S + (size_t)b * S;
#pragma unroll
    for (int nt = 0; nt < 4; ++nt)
#pragma unroll
        for (int r = 0; r < 4; ++r)
            po[(zb + rowbase + (lg << 2) + r) * 64 + nt * 16 + q16] = f2bf(o[nt][r]);
    if (lg == 0) {
        ml[(zb + rowbase + q16) * 2 + 0] = m;
        ml[(zb + rowbase + q16) * 2 + 1] = l;
    }
}

// ---------------- merge: out = sum_z c_z * o_z / sum_z c_z * l_z ----------------
__global__ __launch_bounds__(256) void merge_kernel(
    const ushort_t* __restrict__ po, const float* __restrict__ ml,
    float* __restrict__ out)
{
    const int idx = blockIdx.x * 256 + threadIdx.x;   // 0 .. B*S*8-1
    const int row = idx >> 3, c8 = idx & 7;

    float mv[SPLIT], lv[SPLIT];
#pragma unroll
    for (int zz = 0; zz < SPLIT; ++zz) {
        const float2 t = *(const float2*)(ml + ((size_t)zz * B * S + row) * 2);
        mv[zz] = t.x; lv[zz] = t.y;
    }
    const float mm = fmaxf(fmaxf(mv[0], mv[1]), fmaxf(mv[2], mv[3]));
    float L = 0.f, cz[SPLIT];
#pragma unroll
    for (int zz = 0; zz < SPLIT; ++zz) { cz[zz] = exp2f(mv[zz] - mm); L += lv[zz] * cz[zz]; }
    const float inv = 1.0f / L;

    float acc[8];
#pragma unroll
    for (int e = 0; e < 8; ++e) acc[e] = 0.f;
#pragma unroll
    for (int zz = 0; zz < SPLIT; ++zz) {
        const uint4 pk = *(const uint4*)(po + ((size_t)zz * B * S + row) * 64 + c8 * 8);
        const unsigned w[4] = {pk.x, pk.y, pk.z, pk.w};
#pragma unroll
        for (int i = 0; i < 4; ++i) {
            acc[2 * i + 0] += cz[zz] * __uint_as_float((w[i] & 0xFFFFu) << 16);
            acc[2 * i + 1] += cz[zz] * __uint_as_float((w[i] >> 16) << 16);
        }
    }
    float4 o0 = make_float4(acc[0] * inv, acc[1] * inv, acc[2] * inv, acc[3] * inv);
    float4 o1 = make_float4(acc[4] * inv, acc[5] * inv, acc[6] * inv, acc[7] * inv);
    *(float4*)(out + (size_t)row * 64 + c8 * 8 + 0) = o0;
    *(float4*)(out + (size_t)row * 64 + c8 * 8 + 4) = o1;
}

extern "C" void kernel_launch(void* const* d_in, const int* in_sizes, int n_in,
                              void* d_out, int out_size, void* d_ws, size_t ws_size,
                              hipStream_t stream) {
    const float* x  = (const float*)d_in[0];
    const float* Wq = (const float*)d_in[1];
    const float* bq = (const float*)d_in[2];
    const float* Wk = (const float*)d_in[3];
    const float* bk = (const float*)d_in[4];
    const float* Wv = (const float*)d_in[5];
    const float* bv = (const float*)d_in[6];
    float* out = (float*)d_out;

    char* ws = (char*)d_ws;
    ushort_t* wbt = (ushort_t*)(ws + WBT_OFF);
    ushort_t* qbp = (ushort_t*)(ws + QB_OFF);
    ushort_t* kbp = (ushort_t*)(ws + KB_OFF);
    ushort_t* vtp = (ushort_t*)(ws + VT_OFF);
    float*    mlp = (float*)(ws + ML_OFF);
    ushort_t* pop = (ushort_t*)(ws + PO_OFF);

    hipLaunchKernelGGL(prep_w_kernel, dim3(192), dim3(256), 0, stream, Wq, Wk, Wv, wbt);
    hipLaunchKernelGGL(qkv_mfma_kernel, dim3(512), dim3(512), 0, stream,
                       x, wbt, bq, bk, bv, qbp, kbp, vtp);
    hipLaunchKernelGGL(attn_mfma_kernel, dim3(1024), dim3(256), 0, stream,
                       qbp, kbp, vtp, pop, mlp);
    hipLaunchKernelGGL(merge_kernel, dim3(512), dim3(256), 0, stream, pop, mlp, out);
}

// Round 20
// 64.477 us; speedup vs baseline: 1.0430x; 1.0016x over previous
//
#include <hip/hip_runtime.h>

typedef __attribute__((ext_vector_type(4))) float f32x4;
typedef __attribute__((ext_vector_type(8))) short short8;
typedef unsigned short ushort_t;

constexpr int DM = 1024, DH = 64, S = 4096, B = 4;
// fold softmax scale 1/sqrt(64) AND log2(e) into Q so scores are in exp2 units
constexpr float QSCALE = 0.125f * 1.44269504088896340736f;
constexpr int SPLIT = 4;

// ws layout (bytes)
constexpr size_t WBT_OFF = 0;                    // Wbt: [192][1024] bf16 (W transposed)
constexpr size_t QB_OFF  = 393216;               // Qb:  [B*S][64] bf16, pre-scaled
constexpr size_t KB_OFF  = QB_OFF + 2097152;     // Kb:  [B*S][64] bf16, LINEAR
constexpr size_t VT_OFF  = KB_OFF + 2097152;     // Vtb: [B][64][S] bf16, LINEAR
constexpr size_t ML_OFF  = VT_OFF + 2097152;     // ml:  f32 [4][B*S][2]  = 512KB
constexpr size_t PO_OFF  = ML_OFF + 524288;      // po:  bf16 [4][B*S][64] = 8MB

__device__ __forceinline__ ushort_t f2bf(float f) {  // RNE f32->bf16
    unsigned u = __float_as_uint(f);
    u += 0x7FFFu + ((u >> 16) & 1u);
    return (ushort_t)(u >> 16);
}

__device__ __forceinline__ unsigned cvt_pk_bf16(float lo, float hi) {
    unsigned r;
    asm volatile("v_cvt_pk_bf16_f32 %0, %1, %2" : "=v"(r) : "v"(lo), "v"(hi));
    return r;
}

__device__ __forceinline__ void gl_lds16(const void* g, void* l) {
    __builtin_amdgcn_global_load_lds(
        (const __attribute__((address_space(1))) unsigned int*)g,
        (__attribute__((address_space(3))) unsigned int*)l, 16, 0, 0);
}

// ---------------- prep: W fp32 [1024][64] -> Wbt bf16 [192][1024] (transposed) ----
__global__ __launch_bounds__(256) void prep_w_kernel(
    const float* __restrict__ Wq, const float* __restrict__ Wk,
    const float* __restrict__ Wv, ushort_t* __restrict__ wbt)
{
    const int n = blockIdx.x;            // 0..191 : [Q(0-63)|K(64-127)|V(128-191)]
    const int p = n >> 6, d = n & 63;
    const float* W = (p == 0) ? Wq : (p == 1) ? Wk : Wv;
    const int k0 = threadIdx.x * 4;
    ushort4 pack;
    pack.x = f2bf(W[(k0 + 0) * DH + d]);
    pack.y = f2bf(W[(k0 + 1) * DH + d]);
    pack.z = f2bf(W[(k0 + 2) * DH + d]);
    pack.w = f2bf(W[(k0 + 3) * DH + d]);
    *reinterpret_cast<ushort4*>(wbt + (size_t)n * DM + k0) = pack;
}

// ---------------- QKV projection: cooperative staged GEMM (R10 best, 8-wave) ------
__global__ __launch_bounds__(512, 4) void qkv_mfma_kernel(
    const float* __restrict__ x, const ushort_t* __restrict__ wbt,
    const float* __restrict__ bq, const float* __restrict__ bk,
    const float* __restrict__ bv,
    ushort_t* __restrict__ qb, ushort_t* __restrict__ kb, ushort_t* __restrict__ vt)
{
    __shared__ uint4 AsU[2][256];   // 2 x 4KB : [32 r][128B], 16B-chunk swz ch^(row&7)
    __shared__ uint4 BsU[2][768];   // 2 x 12KB: [192 n][64B], 16B-chunk swz ch^(row&3)

    const int tid = threadIdx.x;
    const int wid = tid >> 6, lane = tid & 63;
    const int q16 = lane & 15, lg = lane >> 4;
    const int sub = wid & 1, np = wid >> 1;
    const int r0 = blockIdx.x * 32;
    const char* xB = (const char*)x;
    const char* wB = (const char*)wbt;

    auto task = [&](int tk, int buf, int kk) {
        if (tk < 4) {
            gl_lds16(xB + (size_t)(r0 + tk * 8 + (lane >> 3)) * 4096 + kk * 4
                        + (((lane & 7) ^ (lane >> 3)) << 4),
                     (char*)&AsU[buf][0] + tk * 1024 + lane * 16);
        } else {
            const int sg = tk - 4;   // B seg 0..11 (1KB = 16 n-rows x 64B)
            gl_lds16(wB + (size_t)(sg * 16 + (lane >> 2)) * 2048 + kk * 2
                        + ((((lane & 3) ^ ((lane >> 2) & 3))) << 4),
                     (char*)&BsU[buf][0] + sg * 1024 + lane * 16);
        }
    };

    f32x4 acc[3];
#pragma unroll
    for (int j = 0; j < 3; ++j) acc[j] = {0.f, 0.f, 0.f, 0.f};

    task(2 * wid, 0, 0);
    task(2 * wid + 1, 0, 0);
    __syncthreads();

    const int row = sub * 16 + q16;
    for (int s = 0; s < 32; ++s) {
        const int buf = s & 1;
        if (s + 1 < 32) {
            task(2 * wid, buf ^ 1, (s + 1) * 32);
            task(2 * wid + 1, buf ^ 1, (s + 1) * 32);
        }
        const char* AsC = (const char*)&AsU[buf][0];
        const char* BsC = (const char*)&BsU[buf][0];
        const f32x4 a0 = *(const f32x4*)(AsC + row * 128 + (((2 * lg) ^ (row & 7)) << 4));
        const f32x4 a1 = *(const f32x4*)(AsC + row * 128 + (((2 * lg + 1) ^ (row & 7)) << 4));
        short8 Af;
        Af[0] = (short)f2bf(a0[0]); Af[1] = (short)f2bf(a0[1]);
        Af[2] = (short)f2bf(a0[2]); Af[3] = (short)f2bf(a0[3]);
        Af[4] = (short)f2bf(a1[0]); Af[5] = (short)f2bf(a1[1]);
        Af[6] = (short)f2bf(a1[2]); Af[7] = (short)f2bf(a1[3]);
        __builtin_amdgcn_s_setprio(1);
#pragma unroll
        for (int j = 0; j < 3; ++j) {
            const int nt = np * 3 + j;
            const short8 Bf = *(const short8*)(
                BsC + (nt * 16 + q16) * 64 + ((lg ^ (q16 & 3)) << 4));
            acc[j] = __builtin_amdgcn_mfma_f32_16x16x32_bf16(Af, Bf, acc[j], 0, 0, 0);
        }
        __builtin_amdgcn_s_setprio(0);
        __syncthreads();
    }

    // Epilogue: C/D layout row=(lane>>4)*4+reg, col=lane&15. Kb/Vt LINEAR.
#pragma unroll
    for (int j = 0; j < 3; ++j) {
        const int nt = np * 3 + j;
        const int p = nt >> 2, d = ((nt & 3) << 4) + q16;
        const float* bp = (p == 0) ? bq : (p == 1) ? bk : bv;
        const float bb = bp[d];
#pragma unroll
        for (int r = 0; r < 4; ++r) {
            const int m = r0 + sub * 16 + (lg << 2) + r;
            const float v = acc[j][r] + bb;
            if (p == 0) {
                qb[(size_t)m * 64 + d] = f2bf(v * QSCALE);
            } else if (p == 1) {
                kb[(size_t)m * 64 + d] = f2bf(v);
            } else {
                const int bb_ = m >> 12, sx = m & 4095;
                vt[(size_t)bb_ * 262144 + (size_t)d * 4096 + sx] = f2bf(v);
            }
        }
    }
}

// ---------------- causal flash attention: QBLK=64, KVBLK=128, split-KV x4 ----------
// R17 body: XCD z-parity KV partition (xcd = 2b + (z&1)) so each XCD's L2 serves
// a 2MB half of the batch's 4MB K/V instead of thrashing at exactly L2 capacity.
__global__ __launch_bounds__(256, 4) void attn_mfma_kernel(
    const ushort_t* __restrict__ qb, const ushort_t* __restrict__ kb,
    const ushort_t* __restrict__ vt, ushort_t* __restrict__ po,
    float* __restrict__ ml)
{
    __shared__ uint4 LsU[2][2048];     // 64KB: [buf][K 16KB | Vt 16KB], 16B slots
    __shared__ uint4 PsU[4][256];      // 16KB: per-wave P [16 q][128 kv] bf16

    const int tid = threadIdx.x;
    const int wid = tid >> 6, lane = tid & 63;
    const int q16 = lane & 15, lg = lane >> 4;

    // XCD-parity decode: xcd = linear&7; b = xcd>>1; z parity tied to xcd parity.
    const int linear = blockIdx.x;            // 0..1023
    const int xcd  = linear & 7;
    const int rest = linear >> 3;             // 0..127
    const int b    = xcd >> 1;
    const int z    = ((rest & 1) << 1) | (xcd & 1);   // 0..3
    const int qt   = 63 - (rest >> 1);        // heavy q-blocks first

    const int qrow = qt * 64 + wid * 16 + q16;   // this lane's q (C/D column)
    const ushort_t* Qb = qb + (size_t)b * S * 64;
    const char* KbB = (const char*)(kb + (size_t)b * S * 64);
    const char* VtB = (const char*)(vt + (size_t)b * 64 * S);

    const short8 qf0 = *(const short8*)(Qb + (size_t)qrow * 64 + lg * 8);
    const short8 qf1 = *(const short8*)(Qb + (size_t)qrow * 64 + 32 + lg * 8);

    f32x4 o[4];
#pragma unroll
    for (int nt = 0; nt < 4; ++nt) o[nt] = {0.f, 0.f, 0.f, 0.f};
    float m = -1e30f, l = 0.f;

    char* PsC = (char*)&PsU[wid][0];
    const int ntiles = (qt >> 1) + 1;            // 128-wide kv tiles

    // Stage tile t (128 kv) into buf: K [128 rows][128B] + Vt [64 d][256B].
    auto stage = [&](int t, int buf) {
        const int kv0 = t * 128;
#pragma unroll
        for (int i = 0; i < 8; ++i) {
            const int slot = i * 256 + tid;
            char* dst = (char*)&LsU[buf][0] + slot * 16;
            if (slot < 1024) {
                const int row = slot >> 3, ch = slot & 7;
                gl_lds16(KbB + (size_t)(kv0 + row) * 128 + ((ch ^ (row & 7)) << 4), dst);
            } else {
                const int s2 = slot - 1024;
                const int d = s2 >> 4, ch = s2 & 15;
                gl_lds16(VtB + (size_t)d * (S * 2) + kv0 * 2 + ((ch ^ (d & 15)) << 4), dst);
            }
        }
    };

    int buf = 0;
    if (z < ntiles) stage(z, 0);
    __syncthreads();

    for (int t = z; t < ntiles; t += SPLIT) {
        if (t + SPLIT < ntiles) stage(t + SPLIT, buf ^ 1);  // overlaps compute below
        const char* KsC = (const char*)&LsU[buf][0];
        const char* VsC = KsC + 16384;
        const int kv0 = t * 128;

        // ---- S^T = K . Q^T : D[kv 128][q 16], lane q=q16, kv = kv0+16mt+4lg+r ----
        f32x4 st[8];
#pragma unroll
        for (int mt = 0; mt < 8; ++mt) st[mt] = {0.f, 0.f, 0.f, 0.f};
#pragma unroll
        for (int ks = 0; ks < 2; ++ks) {
#pragma unroll
            for (int mg = 0; mg < 2; ++mg) {
                short8 kf[4];
#pragma unroll
                for (int j = 0; j < 4; ++j) {
                    const int mt = mg * 4 + j;
                    kf[j] = *(const short8*)(
                        KsC + (mt * 16 + q16) * 128 + (((lg + 4 * ks) ^ (q16 & 7)) << 4));
                }
                __builtin_amdgcn_s_setprio(1);
#pragma unroll
                for (int j = 0; j < 4; ++j)
                    st[mg * 4 + j] = __builtin_amdgcn_mfma_f32_16x16x32_bf16(
                        kf[j], (ks ? qf1 : qf0), st[mg * 4 + j], 0, 0, 0);
                __builtin_amdgcn_s_setprio(0);
            }
        }

        // ---- causal mask: only the diagonal tile (t == ntiles-1) ----
        if (t == ntiles - 1) {
#pragma unroll
            for (int mt = 0; mt < 8; ++mt)
#pragma unroll
                for (int r = 0; r < 4; ++r)
                    if (kv0 + mt * 16 + (lg << 2) + r > qrow) st[mt][r] = -1e30f;
        }

        // ---- online softmax (log2 units), per q-column q16 ----
        float tm = -1e30f;
#pragma unroll
        for (int mt = 0; mt < 8; ++mt)
#pragma unroll
            for (int r = 0; r < 4; ++r) tm = fmaxf(tm, st[mt][r]);
        tm = fmaxf(tm, __shfl_xor(tm, 16));
        tm = fmaxf(tm, __shfl_xor(tm, 32));

        if (__all(tm <= m)) {
            // fast path: running max unchanged -> no rescale, no corr shuffles
            float ps = 0.f;
#pragma unroll
            for (int mt = 0; mt < 8; ++mt)
#pragma unroll
                for (int r = 0; r < 4; ++r) {
                    const float pv = exp2f(st[mt][r] - m);
                    st[mt][r] = pv;
                    ps += pv;
                }
            ps += __shfl_xor(ps, 16);
            ps += __shfl_xor(ps, 32);
            l += ps;
        } else {
            const float mn = fmaxf(m, tm);
            const float corr = exp2f(m - mn);
            float ps = 0.f;
#pragma unroll
            for (int mt = 0; mt < 8; ++mt)
#pragma unroll
                for (int r = 0; r < 4; ++r) {
                    const float pv = exp2f(st[mt][r] - mn);
                    st[mt][r] = pv;
                    ps += pv;
                }
            ps += __shfl_xor(ps, 16);
            ps += __shfl_xor(ps, 32);
            l = l * corr + ps;
            m = mn;
            // o rows are q = 4lg+r but corr is per q-col q16 -> redistribute.
            float corr_row[4];
#pragma unroll
            for (int r = 0; r < 4; ++r) corr_row[r] = __shfl(corr, (lg << 2) | r);
#pragma unroll
            for (int nt = 0; nt < 4; ++nt)
#pragma unroll
                for (int r = 0; r < 4; ++r) o[nt][r] *= corr_row[r];
        }

        // ---- P (bf16 via cvt_pk) -> per-wave LDS [16q][256B], swizzled chunks ----
#pragma unroll
        for (int mt = 0; mt < 8; ++mt) {
            uint2 w;
            w.x = cvt_pk_bf16(st[mt][0], st[mt][1]);
            w.y = cvt_pk_bf16(st[mt][2], st[mt][3]);
            const int ch = (2 * mt + (lg >> 1)) ^ q16;
            *reinterpret_cast<uint2*>(PsC + q16 * 256 + ch * 16 + (lg & 1) * 8) = w;
        }

        // ---- O += P . V : D[q][d], 4 ks-slices of 32 kv ----
        __builtin_amdgcn_s_setprio(1);
#pragma unroll
        for (int ks = 0; ks < 4; ++ks) {
            const short8 pa = *reinterpret_cast<const short8*>(
                PsC + q16 * 256 + (((4 * ks + lg) ^ q16) << 4));
#pragma unroll
            for (int nt = 0; nt < 4; ++nt) {
                const short8 vf = *(const short8*)(
                    VsC + (nt * 16 + q16) * 256 + (((ks * 4 + lg) ^ q16) << 4));
                o[nt] = __builtin_amdgcn_mfma_f32_16x16x32_bf16(pa, vf, o[nt], 0, 0, 0);
            }
        }
        __builtin_amdgcn_s_setprio(0);

        __syncthreads();   // drains stage vmcnt; guards buf reuse
        buf ^= 1;
    }

    // ---- partial write: o unnormalized (bf16), (m,l) f32; each wave owns rows ----
    const int rowbase = qt * 64 + wid * 16;
    const size_t zb = (size_t)z * B * S + (size_t)b * S;
#pragma unroll
    for (int nt = 0; nt < 4; ++nt)
#pragma unroll
        for (int r = 0; r < 4; ++r)
            po[(zb + rowbase + (lg << 2) + r) * 64 + nt * 16 + q16] = f2bf(o[nt][r]);
    if (lg == 0) {
        ml[(zb + rowbase + q16) * 2 + 0] = m;
        ml[(zb + rowbase + q16) * 2 + 1] = l;
    }
}

// ---------------- merge: out = sum_z c_z * o_z / sum_z c_z * l_z ----------------
__global__ __launch_bounds__(256) void merge_kernel(
    const ushort_t* __restrict__ po, const float* __restrict__ ml,
    float* __restrict__ out)
{
    const int idx = blockIdx.x * 256 + threadIdx.x;   // 0 .. B*S*8-1
    const int row = idx >> 3, c8 = idx & 7;

    float mv[SPLIT], lv[SPLIT];
#pragma unroll
    for (int zz = 0; zz < SPLIT; ++zz) {
        const float2 t = *(const float2*)(ml + ((size_t)zz * B * S + row) * 2);
        mv[zz] = t.x; lv[zz] = t.y;
    }
    const float mm = fmaxf(fmaxf(mv[0], mv[1]), fmaxf(mv[2], mv[3]));
    float L = 0.f, cz[SPLIT];
#pragma unroll
    for (int zz = 0; zz < SPLIT; ++zz) { cz[zz] = exp2f(mv[zz] - mm); L += lv[zz] * cz[zz]; }
    const float inv = 1.0f / L;

    float acc[8];
#pragma unroll
    for (int e = 0; e < 8; ++e) acc[e] = 0.f;
#pragma unroll
    for (int zz = 0; zz < SPLIT; ++zz) {
        const uint4 pk = *(const uint4*)(po + ((size_t)zz * B * S + row) * 64 + c8 * 8);
        const unsigned w[4] = {pk.x, pk.y, pk.z, pk.w};
#pragma unroll
        for (int i = 0; i < 4; ++i) {
            acc[2 * i + 0] += cz[zz] * __uint_as_float((w[i] & 0xFFFFu) << 16);
            acc[2 * i + 1] += cz[zz] * __uint_as_float((w[i] >> 16) << 16);
        }
    }
    float4 o0 = make_float4(acc[0] * inv, acc[1] * inv, acc[2] * inv, acc[3] * inv);
    float4 o1 = make_float4(acc[4] * inv, acc[5] * inv, acc[6] * inv, acc[7] * inv);
    *(float4*)(out + (size_t)row * 64 + c8 * 8 + 0) = o0;
    *(float4*)(out + (size_t)row * 64 + c8 * 8 + 4) = o1;
}

extern "C" void kernel_launch(void* const* d_in, const int* in_sizes, int n_in,
                              void* d_out, int out_size, void* d_ws, size_t ws_size,
                              hipStream_t stream) {
    const float* x  = (const float*)d_in[0];
    const float* Wq = (const float*)d_in[1];
    const float* bq = (const float*)d_in[2];
    const float* Wk = (const float*)d_in[3];
    const float* bk = (const float*)d_in[4];
    const float* Wv = (const float*)d_in[5];
    const float* bv = (const float*)d_in[6];
    float* out = (float*)d_out;

    char* ws = (char*)d_ws;
    ushort_t* wbt = (ushort_t*)(ws + WBT_OFF);
    ushort_t* qbp = (ushort_t*)(ws + QB_OFF);
    ushort_t* kbp = (ushort_t*)(ws + KB_OFF);
    ushort_t* vtp = (ushort_t*)(ws + VT_OFF);
    float*    mlp = (float*)(ws + ML_OFF);
    ushort_t* pop = (ushort_t*)(ws + PO_OFF);

    hipLaunchKernelGGL(prep_w_kernel, dim3(192), dim3(256), 0, stream, Wq, Wk, Wv, wbt);
    hipLaunchKernelGGL(qkv_mfma_kernel, dim3(512), dim3(512), 0, stream,
                       x, wbt, bq, bk, bv, qbp, kbp, vtp);
    hipLaunchKernelGGL(attn_mfma_kernel, dim3(1024), dim3(256), 0, stream,
                       qbp, kbp, vtp, pop, mlp);
    hipLaunchKernelGGL(merge_kernel, dim3(512), dim3(256), 0, stream, pop, mlp, out);
}